// Round 10
// baseline (610.545 us; speedup 1.0000x reference)
//
#include <hip/hip_runtime.h>
#include <hip/hip_bf16.h>

typedef unsigned short ushort_t;
typedef __attribute__((ext_vector_type(8))) short short8;
typedef __attribute__((ext_vector_type(8))) unsigned short ushort8;
typedef __attribute__((ext_vector_type(4))) float f32x4;
typedef long long i64;

__device__ __forceinline__ ushort_t f2bf(float f) {
  union { float f; unsigned int u; } c; c.f = f;
  unsigned int u = c.u;
  return (ushort_t)((u + 0x7fffu + ((u >> 16) & 1u)) >> 16);
}
__device__ __forceinline__ float bfu(ushort_t u) {
  union { unsigned int u; float f; } c; c.u = ((unsigned int)u) << 16; return c.f;
}

__device__ __forceinline__ void gload_lds16(const void* g, void* l) {
  __builtin_amdgcn_global_load_lds(
      (__attribute__((address_space(1))) void*)(void*)g,
      (__attribute__((address_space(3))) void*)l, 16, 0, 0);
}

__device__ __forceinline__ void bar_lds() {
  asm volatile("s_waitcnt lgkmcnt(0)" ::: "memory");
  __builtin_amdgcn_s_barrier();
  asm volatile("" ::: "memory");
}

// swizzled fragment read (16B granule XOR within 128B row), elem units
#define GFRAG(p, row, g) \
  (*(const short8*)((p) + (row)*64 + ((((g) ^ ((row)&7))) << 3)))

// ---------------- LayerNorm: f32 in -> bf16 out, D=512, one row per wave ----
__global__ __launch_bounds__(256) void ln_kernel(
    const float* __restrict__ x, const float* __restrict__ g,
    const float* __restrict__ be, ushort_t* __restrict__ out)
{
  const int lane = threadIdx.x & 63, wid = threadIdx.x >> 6;
  const size_t row = (size_t)blockIdx.x * 4 + wid;
  const float* xr = x + row * 512 + lane * 8;
  float4 v0 = *(const float4*)xr;
  float4 v1 = *(const float4*)(xr + 4);
  float vv[8] = {v0.x,v0.y,v0.z,v0.w,v1.x,v1.y,v1.z,v1.w};
  float s = 0;
#pragma unroll
  for (int e = 0; e < 8; ++e) s += vv[e];
#pragma unroll
  for (int o = 1; o < 64; o <<= 1) s += __shfl_xor(s, o);
  float mu = s * (1.0f/512.0f);
  float sq = 0;
#pragma unroll
  for (int e = 0; e < 8; ++e) { float d = vv[e]-mu; sq += d*d; }
#pragma unroll
  for (int o = 1; o < 64; o <<= 1) sq += __shfl_xor(sq, o);
  float rinv = rsqrtf(sq * (1.0f/512.0f) + 1e-5f);
  const float* gp = g + lane*8; const float* bp = be + lane*8;
  float4 ga = *(const float4*)gp, gb = *(const float4*)(gp+4);
  float4 ba = *(const float4*)bp, bb4 = *(const float4*)(bp+4);
  float gg[8] = {ga.x,ga.y,ga.z,ga.w,gb.x,gb.y,gb.z,gb.w};
  float bb[8] = {ba.x,ba.y,ba.z,ba.w,bb4.x,bb4.y,bb4.z,bb4.w};
  ushort8 o8;
#pragma unroll
  for (int e = 0; e < 8; ++e) o8[e] = f2bf((vv[e]-mu)*rinv*gg[e] + bb[e]);
  *(ushort8*)(out + row*512 + lane*8) = o8;
}

// ---------------- Weight transpose (tiled, coalesced both sides) -----------
__global__ __launch_bounds__(256) void wt_kernel(
    const float* __restrict__ w, ushort_t* __restrict__ wT, int K, int N)
{
  __shared__ float t[64][65];
  const int k0 = blockIdx.x * 64, n0 = blockIdx.y * 64;
  const int c = threadIdx.x & 63, r4 = threadIdx.x >> 6;
#pragma unroll
  for (int rr = 0; rr < 64; rr += 4)
    t[rr + r4][c] = w[(size_t)(k0 + rr + r4) * N + n0 + c];
  __syncthreads();
#pragma unroll
  for (int rr = 0; rr < 64; rr += 4)
    wT[(size_t)(n0 + rr + r4) * K + k0 + c] = f2bf(t[c][rr + r4]);
}

// ---------------- Rel-table prep ------------------------------------------
// rqp/rkp: (r,d) bf16, 256 rows (zero-padded >=225); rqp pre-scaled 0.125
// rv8    : (d,r) fp8 e4m3, 64 x 256
// c0_s   : f32[256] = 0.125 * rel_q[r].rel_k[r] (0 for r>=225)
__global__ __launch_bounds__(256) void prep_rel_kernel(
    const float* __restrict__ rq, const float* __restrict__ rk,
    const float* __restrict__ rv,
    ushort_t* __restrict__ rqp, ushort_t* __restrict__ rkp,
    unsigned char* __restrict__ rv8, float* __restrict__ c0_s)
{
  int id = blockIdx.x * 256 + threadIdx.x;
  if (id < 256*64) {
    int r = id >> 6;
    rqp[id] = (r < 225) ? f2bf(rq[id] * 0.125f) : (ushort_t)0;
    rkp[id] = (r < 225) ? f2bf(rk[id]) : (ushort_t)0;
  }
  if (id < 64*256) {
    int d = id >> 8, r = id & 255;
    float vv = (r < 225) ? rv[r*64+d] : 0.0f;
    int pk = __builtin_amdgcn_cvt_pk_fp8_f32(vv, vv, 0, 0);
    rv8[id] = (unsigned char)(pk & 0xff);
  }
  if (id < 256) {
    float s = 0;
    if (id < 225)
      for (int d2 = 0; d2 < 64; ++d2) s += rq[id*64+d2]*rk[id*64+d2];
    c0_s[id] = s * 0.125f;
  }
}

// ---------------- bf16 GEMM: 256x256 tile, BK=64, 512 thr, 128KB LDS -------
template<int EPI>
__global__ __launch_bounds__(512, 2) void gemm_kernel(
    const ushort_t* __restrict__ A, const ushort_t* __restrict__ Bt,
    int M, int N, int K,
    const float* __restrict__ bias, const float* __restrict__ resid,
    float* __restrict__ outf, ushort_t* __restrict__ outb,
    ushort_t* __restrict__ qb, ushort_t* __restrict__ kb,
    ushort_t* __restrict__ vtb)
{
  __shared__ __align__(16) ushort_t lds[65536];  // 2 x (A 32KB + B 32KB)
  const int tid = threadIdx.x, lane = tid & 63, wid = tid >> 6;
  const int m0 = blockIdx.x * 256, n0 = blockIdx.y * 256;
  const int l15 = lane & 15, lh = lane >> 4;
  const int wm = wid >> 2, wn = wid & 3;

  f32x4 acc[8][4] = {};
  const int NT = K >> 6;

  auto stage = [&](int buf, int kt) {
    const int k0 = kt << 6;
#pragma unroll
    for (int p = 0; p < 4; ++p) {
      const int lofs = p*8192 + tid*16;            // byte offset in 32KB half
      const int row = lofs >> 7;                   // 0..255
      const int sc = ((tid & 7) ^ (row & 7)) << 3; // swizzled src col (elems)
      gload_lds16(A  + (size_t)(m0 + row) * K + (k0 + sc),
                  &lds[buf*32768 + (lofs >> 1)]);
      gload_lds16(Bt + (size_t)(n0 + row) * K + (k0 + sc),
                  &lds[buf*32768 + 16384 + (lofs >> 1)]);
    }
  };

  stage(0, 0);
  __syncthreads();
  for (int t = 0; t < NT; ++t) {
    if (t + 1 < NT) stage((t+1) & 1, t+1);
    const ushort_t* Ab = &lds[(t&1)*32768];
    const ushort_t* Bb = Ab + 16384;
    short8 bfr[4][2];
#pragma unroll
    for (int ni = 0; ni < 4; ++ni) {
      const int row = wn*64 + ni*16 + l15;
#pragma unroll
      for (int kh = 0; kh < 2; ++kh)
        bfr[ni][kh] = *(const short8*)((const char*)Bb + row*128 +
                                       (((kh*4+lh) ^ (row&7))<<4));
    }
#pragma unroll
    for (int mi = 0; mi < 8; ++mi) {
      const int row = wm*128 + mi*16 + l15;
      short8 a0 = *(const short8*)((const char*)Ab + row*128 + ((lh     ^ (row&7))<<4));
      short8 a1 = *(const short8*)((const char*)Ab + row*128 + (((4+lh) ^ (row&7))<<4));
#pragma unroll
      for (int ni = 0; ni < 4; ++ni) {
        acc[mi][ni] = __builtin_amdgcn_mfma_f32_16x16x32_bf16(a0, bfr[ni][0], acc[mi][ni], 0,0,0);
        acc[mi][ni] = __builtin_amdgcn_mfma_f32_16x16x32_bf16(a1, bfr[ni][1], acc[mi][ni], 0,0,0);
      }
    }
    __syncthreads();
  }

#pragma unroll
  for (int mi = 0; mi < 8; ++mi)
#pragma unroll
    for (int ni = 0; ni < 4; ++ni)
#pragma unroll
      for (int r = 0; r < 4; ++r) {
        const int grow = m0 + wm*128 + mi*16 + lh*4 + r;
        const int gcol = n0 + wn*64 + ni*16 + l15;
        const float v = acc[mi][ni][r];
        if constexpr (EPI == 0) {
          const int sel = gcol >> 9, c5 = gcol & 511;
          const int hh = c5 >> 6, d = c5 & 63;
          const size_t bh = (size_t)((grow >> 6) * 8 + hh);
          const int i = grow & 63;
          if (sel == 0)
            qb[(bh<<12) + i*64 + (((d>>3)^(i&7))<<3) + (d&7)] = f2bf(v * 0.125f);
          else if (sel == 1)
            kb[(bh<<12) + i*64 + (((d>>3)^(i&7))<<3) + (d&7)] = f2bf(v);
          else
            vtb[(bh<<12) + d*64 + i] = f2bf(v);
        } else if constexpr (EPI == 2) {
          float t2 = v + bias[gcol];
          outb[(size_t)grow * N + gcol] = f2bf(t2 > 0.0f ? t2 : 0.0f);
        } else {
          const size_t o = (size_t)grow * N + gcol;
          outf[o] = v + bias[gcol] + resid[o];
        }
      }
}

// ---------------- Fused relative attention --------------------------------
// One head per 512-thread block (8 waves; wave = (ib, half)).
// Windowed rel-terms: rr(i,j) = base_i + c_j, c_j compile-time per j.
//  t2w[i][rr-base_i]  (64 x 240B rows, c0 folded at store)
//  t3t[rr-112+base_j][j] (113 x 128B swizzled rows) -> softmax reads are
//  1 add + 1 u16 (t2) and one aligned 16B vector (t3).
// LDS 46208B -> 3 blocks/CU. q/k fragments direct from swizzled global.
__global__ __launch_bounds__(512, 6) void attn_kernel(
    const ushort_t* __restrict__ qb, const ushort_t* __restrict__ kb,
    const ushort_t* __restrict__ vtb,
    const ushort_t* __restrict__ rkp, const ushort_t* __restrict__ rqp,
    const unsigned char* __restrict__ rv8, const float* __restrict__ c0_g,
    ushort_t* __restrict__ attn_out)
{
  __shared__ __align__(16) char smem[46208];
  char* t2w = smem;             // 15360: 64 rows x 240B
  char* t3t = smem + 15360;     // 14464: 113 rows x 128B (XOR swz)
  char* qkB = smem + 29824;     // 16384: 64 rows x 256B f32 (XOR swz)
  char* attnSB = smem;          // overlay post-softmax (8K)
  char* S8B = smem + 8192;      // overlay post-softmax (16K)

  const int tid = threadIdx.x, lane = tid & 63, wid = tid >> 6;
  const int ib = wid >> 1, half = wid & 1;
  const int l15 = lane & 15, lh = lane >> 4;
  const int rowA = ib*16 + l15;
  const int bh = blockIdx.x;
  const ushort_t* q = qb + ((size_t)bh << 12);
  const ushort_t* k = kb + ((size_t)bh << 12);

  // q/k fragments straight from L2 (tiles are XOR-pre-swizzled by GEMM)
  short8 qf0 = GFRAG(q, rowA, lh);
  short8 qf1 = GFRAG(q, rowA, 4+lh);
  short8 kf0 = GFRAG(k, rowA, lh);
  short8 kf1 = GFRAG(k, rowA, 4+lh);

  const int ibase = ib*16 + lh*4;
  int baseR[4], i240[4];
#pragma unroll
  for (int r = 0; r < 4; ++r) {
    const int i = ibase + r;
    baseR[r] = (i >> 3)*15 + (i & 7);
    i240[r] = i*240;
  }

  // ---- P1a: QK^T (wave pair splits jb), store to qkB ---------------------
#pragma unroll
  for (int t = 0; t < 2; ++t) {
    const int jb = half*2 + t;
    const int rowK = jb*16 + l15;
    short8 b0 = GFRAG(k, rowK, lh);
    short8 b1 = GFRAG(k, rowK, 4+lh);
    f32x4 a = {};
    a = __builtin_amdgcn_mfma_f32_16x16x32_bf16(qf0, b0, a, 0,0,0);
    a = __builtin_amdgcn_mfma_f32_16x16x32_bf16(qf1, b1, a, 0,0,0);
#pragma unroll
    for (int r = 0; r < 4; ++r) {
      const int i = ibase + r;
      const int gcol = jb*16 + l15;
      *(float*)(qkB + i*256 + ((((gcol>>2) ^ (i&7)))<<4) + (gcol&3)*4) = a[r];
    }
  }

  // ---- P1b: t2 = q @ rel_k^T, windowed store (c0 folded) -----------------
#pragma unroll
  for (int sp = 0; sp < 4; ++sp) {
    int rowr[2]; short8 lb[4]; float c0v[2];
#pragma unroll
    for (int cc = 0; cc < 2; ++cc) {
      rowr[cc] = (half*8 + sp*2 + cc)*16 + l15;
      lb[cc*2]   = *(const short8*)(rkp + rowr[cc]*64 + lh*8);
      lb[cc*2+1] = *(const short8*)(rkp + rowr[cc]*64 + 32 + lh*8);
      c0v[cc] = c0_g[rowr[cc]];
    }
    f32x4 a2[2] = {};
#pragma unroll
    for (int cc = 0; cc < 2; ++cc) {
      a2[cc] = __builtin_amdgcn_mfma_f32_16x16x32_bf16(qf0, lb[cc*2],   a2[cc], 0,0,0);
      a2[cc] = __builtin_amdgcn_mfma_f32_16x16x32_bf16(qf1, lb[cc*2+1], a2[cc], 0,0,0);
    }
#pragma unroll
    for (int cc = 0; cc < 2; ++cc)
#pragma unroll
      for (int r = 0; r < 4; ++r) {
        const unsigned c = (unsigned)(rowr[cc] - baseR[r]);
        if (c <= 112u)
          *(ushort_t*)(t2w + i240[r] + c*2) = f2bf(a2[cc][r] + c0v[cc]);
      }
  }

  // ---- P1c: t3 = k @ rel_q^T (pre-scaled), transposed windowed store -----
#pragma unroll
  for (int sp = 0; sp < 4; ++sp) {
    int rowr[2]; short8 lb[4];
#pragma unroll
    for (int cc = 0; cc < 2; ++cc) {
      rowr[cc] = (half*8 + sp*2 + cc)*16 + l15;
      lb[cc*2]   = *(const short8*)(rqp + rowr[cc]*64 + lh*8);
      lb[cc*2+1] = *(const short8*)(rqp + rowr[cc]*64 + 32 + lh*8);
    }
    f32x4 a3[2] = {};
#pragma unroll
    for (int cc = 0; cc < 2; ++cc) {
      a3[cc] = __builtin_amdgcn_mfma_f32_16x16x32_bf16(kf0, lb[cc*2],   a3[cc], 0,0,0);
      a3[cc] = __builtin_amdgcn_mfma_f32_16x16x32_bf16(kf1, lb[cc*2+1], a3[cc], 0,0,0);
    }
#pragma unroll
    for (int cc = 0; cc < 2; ++cc)
#pragma unroll
      for (int r = 0; r < 4; ++r) {
        const int j = ibase + r;
        const unsigned w = (unsigned)(rowr[cc] - 112 + baseR[r]);
        if (w <= 112u)
          *(ushort_t*)(t3t + w*128 + ((j*2) ^ ((w&7)<<4))) = f2bf(a3[cc][r]);
      }
  }
  bar_lds();  // BAR1: qk/t2w/t3t complete

  // ---- P2: softmax --------------------------------------------------------
  const int i = tid >> 3, qq = tid & 7;
  const int base_i = (i >> 3)*15 + (i & 7);
  float av[8];
  {
    const char* t2row = t2w + i*240;
    const int cb = (7-qq)*15 + 7;
    ushort8 t3v = *(const ushort8*)(t3t + base_i*128 + ((qq*16) ^ ((base_i&7)<<4)));
    float mx = -1e30f;
#pragma unroll
    for (int h = 0; h < 2; ++h) {
      const int g = 2*qq + h;
      f32x4 lf = *(const f32x4*)(qkB + i*256 + ((g ^ (i&7))<<4));
#pragma unroll
      for (int e = 0; e < 4; ++e) {
        const int jj = h*4 + e;
        float v = lf[e] + bfu(*(const ushort_t*)(t2row + (cb - jj)*2))
                        + bfu((ushort_t)t3v[jj]);
        av[jj] = v; mx = fmaxf(mx, v);
      }
    }
    mx = fmaxf(mx, __shfl_xor(mx, 1));
    mx = fmaxf(mx, __shfl_xor(mx, 2));
    mx = fmaxf(mx, __shfl_xor(mx, 4));
    float s = 0;
#pragma unroll
    for (int e = 0; e < 8; ++e) { float ev = __expf(av[e]-mx); av[e] = ev; s += ev; }
    s += __shfl_xor(s, 1); s += __shfl_xor(s, 2); s += __shfl_xor(s, 4);
    const float inv = 1.0f / s;
#pragma unroll
    for (int e = 0; e < 8; ++e) av[e] *= inv;
  }
  bar_lds();  // BAR2: all reads done; overlay may be rewritten

  // ---- P3: write attnS (bf16) + S8 (fp8 scatter, rr = rrb - jj) ----------
  {
    ushort8 w;
#pragma unroll
    for (int e = 0; e < 8; ++e) w[e] = f2bf(av[e]);
    *(ushort8*)(attnSB + i*128 + ((qq ^ (i&7))<<4)) = w;
#pragma unroll
    for (int u8 = 0; u8 < 4; ++u8)
      *(i64*)(S8B + i*256 + (((qq*4 + u8) ^ (i&7))<<3)) = 0;
    const int rrb = base_i + (7-qq)*15 + 7;
#pragma unroll
    for (int jj = 0; jj < 8; jj += 2) {
      int pk = __builtin_amdgcn_cvt_pk_fp8_f32(av[jj], av[jj+1], 0, 0);
      const int rr0 = rrb - jj;
      const int rr1 = rr0 - 1;
      *(unsigned char*)(S8B + i*256 + (((rr0>>3) ^ (i&7))<<3) + (rr0&7))
          = (unsigned char)(pk & 0xff);
      *(unsigned char*)(S8B + i*256 + (((rr1>>3) ^ (i&7))<<3) + (rr1&7))
          = (unsigned char)((pk >> 8) & 0xff);
    }
  }
  bar_lds();  // BAR3: attnS/S8 complete (wave-pair reads next)

  // ---- P4: out = attn @ v (bf16) + S @ rel_v^T (fp8), 2 tiles per wave ---
#pragma unroll
  for (int t = 0; t < 2; ++t) {
    const int db = half*2 + t;
    const int rowV = db*16 + l15;
    const ushort_t* vrow = vtb + ((size_t)bh << 12) + rowV*64;
    short8 bv0 = *(const short8*)(vrow + lh*8);
    short8 bv1 = *(const short8*)(vrow + 32 + lh*8);
    i64 b8v[8];
#pragma unroll
    for (int ks = 0; ks < 8; ++ks)
      b8v[ks] = *(const i64*)(rv8 + (size_t)rowV*256 + ks*32 + lh*8);
    f32x4 a = {};
#pragma unroll
    for (int ks = 0; ks < 8; ++ks) {
      i64 a8 = *(const i64*)(S8B + rowA*256 + (((ks*4+lh) ^ (rowA&7))<<3));
      a = __builtin_amdgcn_mfma_f32_16x16x32_fp8_fp8(a8, b8v[ks], a, 0,0,0);
    }
    {
      short8 aa0 = *(const short8*)(attnSB + rowA*128 + ((lh ^ (rowA&7))<<4));
      short8 aa1 = *(const short8*)(attnSB + rowA*128 + (((4+lh) ^ (rowA&7))<<4));
      a = __builtin_amdgcn_mfma_f32_16x16x32_bf16(aa0, bv0, a, 0,0,0);
      a = __builtin_amdgcn_mfma_f32_16x16x32_bf16(aa1, bv1, a, 0,0,0);
    }
    const int b_idx = bh >> 3, hh = bh & 7;
#pragma unroll
    for (int r = 0; r < 4; ++r)
      attn_out[((size_t)(b_idx*64 + ib*16 + lh*4 + r))*512 + hh*64 + db*16 + l15]
          = f2bf(a[r]);
  }
}

// ---------------------------------------------------------------------------
extern "C" void kernel_launch(void* const* d_in, const int* in_sizes, int n_in,
                              void* d_out, int out_size, void* d_ws, size_t ws_size,
                              hipStream_t stream)
{
  (void)in_sizes; (void)n_in; (void)out_size; (void)ws_size;
  const float* x     = (const float*)d_in[0];
  const float* w_qkv = (const float*)d_in[1];
  const float* w_proj= (const float*)d_in[2];
  const float* b_proj= (const float*)d_in[3];
  const float* w1    = (const float*)d_in[4];
  const float* b1    = (const float*)d_in[5];
  const float* w2    = (const float*)d_in[6];
  const float* b2    = (const float*)d_in[7];
  const float* g1    = (const float*)d_in[8];
  const float* be1   = (const float*)d_in[9];
  const float* g2    = (const float*)d_in[10];
  const float* be2   = (const float*)d_in[11];
  const float* rel_q = (const float*)d_in[12];
  const float* rel_k = (const float*)d_in[13];
  const float* rel_v = (const float*)d_in[14];

  char* ws = (char*)d_ws;
  const size_t MB = 1ull << 20;
  ushort_t* h      = (ushort_t*)(ws);            // 32MiB (reused as h2)
  ushort_t* qb     = (ushort_t*)(ws + 32*MB);
  ushort_t* kb     = (ushort_t*)(ws + 64*MB);
  ushort_t* vtb    = (ushort_t*)(ws + 96*MB);
  ushort_t* attn_o = (ushort_t*)(ws + 128*MB);
  ushort_t* ff     = (ushort_t*)(ws + 32*MB);    // aliases qb..attn_o (dead)
  float*    x_mid  = (float*)(ws + 160*MB);      // 64MiB
  char* wreg = ws + 224*MB;
  ushort_t* wqkvT = (ushort_t*)(wreg);
  ushort_t* wprojT= (ushort_t*)(wreg + 1572864);
  ushort_t* w1T   = (ushort_t*)(wreg + 2097152);
  ushort_t* w2T   = (ushort_t*)(wreg + 4194304);
  ushort_t*      rkp  = (ushort_t*)(wreg + 6291456);   // 256x64 bf16
  ushort_t*      rqp  = (ushort_t*)(wreg + 6324224);   // 256x64 bf16
  unsigned char* rv8  = (unsigned char*)(wreg + 6356992); // 64x256 fp8
  float*         c0_s = (float*)(wreg + 6373376);       // f32[256]

  wt_kernel<<<dim3(8,24), 256, 0, stream>>>(w_qkv, wqkvT, 512, 1536);
  wt_kernel<<<dim3(8,8),  256, 0, stream>>>(w_proj, wprojT, 512, 512);
  wt_kernel<<<dim3(8,32), 256, 0, stream>>>(w1, w1T, 512, 2048);
  wt_kernel<<<dim3(32,8), 256, 0, stream>>>(w2, w2T, 2048, 512);
  prep_rel_kernel<<<64, 256, 0, stream>>>(rel_q, rel_k, rel_v,
      rqp, rkp, rv8, c0_s);

  ln_kernel<<<8192, 256, 0, stream>>>(x, g1, be1, h);
  gemm_kernel<0><<<dim3(128,6), 512, 0, stream>>>(h, wqkvT, 32768, 1536, 512,
      nullptr, nullptr, nullptr, nullptr, qb, kb, vtb);
  attn_kernel<<<4096, 512, 0, stream>>>(qb, kb, vtb,
      rkp, rqp, rv8, c0_s, attn_o);
  gemm_kernel<1><<<dim3(128,2), 512, 0, stream>>>(attn_o, wprojT, 32768, 512, 512,
      b_proj, x, x_mid, nullptr, nullptr, nullptr, nullptr);
  ln_kernel<<<8192, 256, 0, stream>>>(x_mid, g2, be2, h);
  gemm_kernel<2><<<dim3(128,8), 512, 0, stream>>>(h, w1T, 32768, 2048, 512,
      b1, nullptr, nullptr, ff, nullptr, nullptr, nullptr);
  gemm_kernel<3><<<dim3(128,2), 512, 0, stream>>>(ff, w2T, 32768, 512, 2048,
      b2, x_mid, (float*)d_out, nullptr, nullptr, nullptr, nullptr);
}

// Round 11
// 603.538 us; speedup vs baseline: 1.0116x; 1.0116x over previous
//
#include <hip/hip_runtime.h>
#include <hip/hip_bf16.h>

typedef unsigned short ushort_t;
typedef __attribute__((ext_vector_type(8))) short short8;
typedef __attribute__((ext_vector_type(8))) unsigned short ushort8;
typedef __attribute__((ext_vector_type(4))) float f32x4;
typedef long long i64;

__device__ __forceinline__ ushort_t f2bf(float f) {
  union { float f; unsigned int u; } c; c.f = f;
  unsigned int u = c.u;
  return (ushort_t)((u + 0x7fffu + ((u >> 16) & 1u)) >> 16);
}
__device__ __forceinline__ float bfu(ushort_t u) {
  union { unsigned int u; float f; } c; c.u = ((unsigned int)u) << 16; return c.f;
}
__device__ __forceinline__ ushort_t f2h(float f) {
  union { _Float16 h; ushort_t u; } c; c.h = (_Float16)f; return c.u;
}
__device__ __forceinline__ float h2f(ushort_t u) {
  union { ushort_t u; _Float16 h; } c; c.u = u; return (float)c.h;
}

__device__ __forceinline__ void gload_lds16(const void* g, void* l) {
  __builtin_amdgcn_global_load_lds(
      (__attribute__((address_space(1))) void*)(void*)g,
      (__attribute__((address_space(3))) void*)l, 16, 0, 0);
}

__device__ __forceinline__ void bar_lds() {
  asm volatile("s_waitcnt lgkmcnt(0)" ::: "memory");
  __builtin_amdgcn_s_barrier();
  asm volatile("" ::: "memory");
}
__device__ __forceinline__ void bar_full() {
  asm volatile("s_waitcnt vmcnt(0) lgkmcnt(0)" ::: "memory");
  __builtin_amdgcn_s_barrier();
  asm volatile("" ::: "memory");
}

// swizzled fragment reads (16B granule XOR within 128B row)
#define GFRAG(p, row, g) \
  (*(const short8*)((p) + (row)*64 + ((((g) ^ ((row)&7))) << 3)))      // elem base
#define LDSF(base, row, g) \
  (*(const short8*)((base) + (row)*128 + ((((g) ^ ((row)&7))) << 4)))  // byte base

// ---------------- LayerNorm: f32 in -> bf16 out, D=512, one row per wave ----
__global__ __launch_bounds__(256) void ln_kernel(
    const float* __restrict__ x, const float* __restrict__ g,
    const float* __restrict__ be, ushort_t* __restrict__ out)
{
  const int lane = threadIdx.x & 63, wid = threadIdx.x >> 6;
  const size_t row = (size_t)blockIdx.x * 4 + wid;
  const float* xr = x + row * 512 + lane * 8;
  float4 v0 = *(const float4*)xr;
  float4 v1 = *(const float4*)(xr + 4);
  float vv[8] = {v0.x,v0.y,v0.z,v0.w,v1.x,v1.y,v1.z,v1.w};
  float s = 0;
#pragma unroll
  for (int e = 0; e < 8; ++e) s += vv[e];
#pragma unroll
  for (int o = 1; o < 64; o <<= 1) s += __shfl_xor(s, o);
  float mu = s * (1.0f/512.0f);
  float sq = 0;
#pragma unroll
  for (int e = 0; e < 8; ++e) { float d = vv[e]-mu; sq += d*d; }
#pragma unroll
  for (int o = 1; o < 64; o <<= 1) sq += __shfl_xor(sq, o);
  float rinv = rsqrtf(sq * (1.0f/512.0f) + 1e-5f);
  const float* gp = g + lane*8; const float* bp = be + lane*8;
  float4 ga = *(const float4*)gp, gb = *(const float4*)(gp+4);
  float4 ba = *(const float4*)bp, bb4 = *(const float4*)(bp+4);
  float gg[8] = {ga.x,ga.y,ga.z,ga.w,gb.x,gb.y,gb.z,gb.w};
  float bb[8] = {ba.x,ba.y,ba.z,ba.w,bb4.x,bb4.y,bb4.z,bb4.w};
  ushort8 o8;
#pragma unroll
  for (int e = 0; e < 8; ++e) o8[e] = f2bf((vv[e]-mu)*rinv*gg[e] + bb[e]);
  *(ushort8*)(out + row*512 + lane*8) = o8;
}

// ---------------- Weight transpose (tiled, coalesced both sides) -----------
__global__ __launch_bounds__(256) void wt_kernel(
    const float* __restrict__ w, ushort_t* __restrict__ wT, int K, int N)
{
  __shared__ float t[64][65];
  const int k0 = blockIdx.x * 64, n0 = blockIdx.y * 64;
  const int c = threadIdx.x & 63, r4 = threadIdx.x >> 6;
#pragma unroll
  for (int rr = 0; rr < 64; rr += 4)
    t[rr + r4][c] = w[(size_t)(k0 + rr + r4) * N + n0 + c];
  __syncthreads();
#pragma unroll
  for (int rr = 0; rr < 64; rr += 4)
    wT[(size_t)(n0 + rr + r4) * K + k0 + c] = f2bf(t[c][rr + r4]);
}

// ---------------- Rel-table prep ------------------------------------------
__global__ __launch_bounds__(256) void prep_rel_kernel(
    const float* __restrict__ rq, const float* __restrict__ rk,
    const float* __restrict__ rv,
    ushort_t* __restrict__ rqp, ushort_t* __restrict__ rkp,
    unsigned char* __restrict__ rv8, float* __restrict__ c0_s)
{
  int id = blockIdx.x * 256 + threadIdx.x;
  if (id < 256*64) {
    int r = id >> 6;
    rqp[id] = (r < 225) ? f2bf(rq[id] * 0.125f) : (ushort_t)0;
    rkp[id] = (r < 225) ? f2bf(rk[id]) : (ushort_t)0;
  }
  if (id < 64*256) {
    int d = id >> 8, r = id & 255;
    float vv = (r < 225) ? rv[r*64+d] : 0.0f;
    int pk = __builtin_amdgcn_cvt_pk_fp8_f32(vv, vv, 0, 0);
    rv8[id] = (unsigned char)(pk & 0xff);
  }
  if (id < 256) {
    float s = 0;
    if (id < 225)
      for (int d2 = 0; d2 < 64; ++d2) s += rq[id*64+d2]*rk[id*64+d2];
    c0_s[id] = s * 0.125f;
  }
}

// ---------------- bf16 GEMM 256x256 tile, BK=64, 512 thr, 128KB LDS --------
// EPI 0: scatter qkv (XOR-swizzled q/k head tiles, linear vT)
// EPI 2: relu(+bias) -> bf16
template<int EPI>
__global__ __launch_bounds__(512, 2) void gemm_kernel(
    const ushort_t* __restrict__ A, const ushort_t* __restrict__ Bt,
    int M, int N, int K,
    const float* __restrict__ bias,
    ushort_t* __restrict__ outb,
    ushort_t* __restrict__ qb, ushort_t* __restrict__ kb,
    ushort_t* __restrict__ vtb)
{
  __shared__ __align__(16) ushort_t lds[65536];  // 2 x (A 32KB + B 32KB)
  const int tid = threadIdx.x, lane = tid & 63, wid = tid >> 6;
  const int m0 = blockIdx.x * 256, n0 = blockIdx.y * 256;
  const int l15 = lane & 15, lh = lane >> 4;
  const int wm = wid >> 2, wn = wid & 3;

  f32x4 acc[8][4] = {};
  const int NT = K >> 6;

  auto stage = [&](int buf, int kt) {
    const int k0 = kt << 6;
#pragma unroll
    for (int p = 0; p < 4; ++p) {
      const int lofs = p*8192 + tid*16;
      const int row = lofs >> 7;
      const int sc = ((tid & 7) ^ (row & 7)) << 3;
      gload_lds16(A  + (size_t)(m0 + row) * K + (k0 + sc),
                  &lds[buf*32768 + (lofs >> 1)]);
      gload_lds16(Bt + (size_t)(n0 + row) * K + (k0 + sc),
                  &lds[buf*32768 + 16384 + (lofs >> 1)]);
    }
  };

  stage(0, 0);
  __syncthreads();
  for (int t = 0; t < NT; ++t) {
    if (t + 1 < NT) stage((t+1) & 1, t+1);
    const ushort_t* Ab = &lds[(t&1)*32768];
    const ushort_t* Bb = Ab + 16384;
    short8 bfr[4][2];
#pragma unroll
    for (int ni = 0; ni < 4; ++ni) {
      const int row = wn*64 + ni*16 + l15;
#pragma unroll
      for (int kh = 0; kh < 2; ++kh)
        bfr[ni][kh] = *(const short8*)((const char*)Bb + row*128 +
                                       (((kh*4+lh) ^ (row&7))<<4));
    }
#pragma unroll
    for (int mi = 0; mi < 8; ++mi) {
      const int row = wm*128 + mi*16 + l15;
      short8 a0 = *(const short8*)((const char*)Ab + row*128 + ((lh     ^ (row&7))<<4));
      short8 a1 = *(const short8*)((const char*)Ab + row*128 + (((4+lh) ^ (row&7))<<4));
#pragma unroll
      for (int ni = 0; ni < 4; ++ni) {
        acc[mi][ni] = __builtin_amdgcn_mfma_f32_16x16x32_bf16(a0, bfr[ni][0], acc[mi][ni], 0,0,0);
        acc[mi][ni] = __builtin_amdgcn_mfma_f32_16x16x32_bf16(a1, bfr[ni][1], acc[mi][ni], 0,0,0);
      }
    }
    __syncthreads();
  }

#pragma unroll
  for (int mi = 0; mi < 8; ++mi)
#pragma unroll
    for (int ni = 0; ni < 4; ++ni)
#pragma unroll
      for (int r = 0; r < 4; ++r) {
        const int grow = m0 + wm*128 + mi*16 + lh*4 + r;
        const int gcol = n0 + wn*64 + ni*16 + l15;
        const float v = acc[mi][ni][r];
        if constexpr (EPI == 0) {
          const int sel = gcol >> 9, c5 = gcol & 511;
          const int hh = c5 >> 6, d = c5 & 63;
          const size_t bh = (size_t)((grow >> 6) * 8 + hh);
          const int i = grow & 63;
          if (sel == 0)
            qb[(bh<<12) + i*64 + (((d>>3)^(i&7))<<3) + (d&7)] = f2bf(v * 0.125f);
          else if (sel == 1)
            kb[(bh<<12) + i*64 + (((d>>3)^(i&7))<<3) + (d&7)] = f2bf(v);
          else
            vtb[(bh<<12) + d*64 + i] = f2bf(v);
        } else {
          float t2 = v + bias[gcol];
          outb[(size_t)grow * N + gcol] = f2bf(t2 > 0.0f ? t2 : 0.0f);
        }
      }
}

// ---------------- bf16 GEMM 128x128 tile (for N=512: avoids tail idle) -----
// outf = A@Bt^T + bias + resid (f32)
__global__ __launch_bounds__(256) void gemm128_br(
    const ushort_t* __restrict__ A, const ushort_t* __restrict__ Bt,
    int M, int N, int K,
    const float* __restrict__ bias, const float* __restrict__ resid,
    float* __restrict__ outf)
{
  __shared__ __align__(16) ushort_t lds[32768];
  const int tid = threadIdx.x, lane = tid & 63, wid = tid >> 6;
  const int m0 = blockIdx.x * 128, n0 = blockIdx.y * 128;
  const int l15 = lane & 15, lh = lane >> 4;
  const int wm = wid >> 1, wn = wid & 1;

  f32x4 acc[4][4] = {};
  const int NT = K >> 6;

  auto stage = [&](int buf, int kt) {
    const int k0 = kt << 6;
#pragma unroll
    for (int p = 0; p < 4; ++p) {
      const int lofs = p*4096 + wid*1024;
      const int row = (lofs + lane*16) >> 7;
      const int sc = ((lane & 7) ^ (row & 7)) << 3;
      gload_lds16(A  + (size_t)(m0 + row) * K + (k0 + sc),
                  &lds[buf*16384 + (lofs >> 1)]);
      gload_lds16(Bt + (size_t)(n0 + row) * K + (k0 + sc),
                  &lds[buf*16384 + 8192 + (lofs >> 1)]);
    }
  };

  stage(0, 0);
  __syncthreads();
  for (int t = 0; t < NT; ++t) {
    if (t + 1 < NT) stage((t+1) & 1, t+1);
    const ushort_t* Ab = &lds[(t&1)*16384];
    const ushort_t* Bb = Ab + 8192;
#pragma unroll
    for (int kh = 0; kh < 2; ++kh) {
      const int slotk = kh*4 + lh;
      short8 af[4], bf[4];
#pragma unroll
      for (int mi = 0; mi < 4; ++mi) {
        int row = wm*64 + mi*16 + l15;
        af[mi] = *(const short8*)((const char*)Ab + row*128 + ((slotk ^ (row&7))<<4));
      }
#pragma unroll
      for (int ni = 0; ni < 4; ++ni) {
        int row = wn*64 + ni*16 + l15;
        bf[ni] = *(const short8*)((const char*)Bb + row*128 + ((slotk ^ (row&7))<<4));
      }
#pragma unroll
      for (int mi = 0; mi < 4; ++mi)
#pragma unroll
        for (int ni = 0; ni < 4; ++ni)
          acc[mi][ni] = __builtin_amdgcn_mfma_f32_16x16x32_bf16(
              af[mi], bf[ni], acc[mi][ni], 0, 0, 0);
    }
    __syncthreads();
  }

#pragma unroll
  for (int mi = 0; mi < 4; ++mi)
#pragma unroll
    for (int ni = 0; ni < 4; ++ni)
#pragma unroll
      for (int r = 0; r < 4; ++r) {
        const int grow = m0 + wm*64 + mi*16 + lh*4 + r;
        const int gcol = n0 + wn*64 + ni*16 + l15;
        const size_t o = (size_t)grow * N + gcol;
        outf[o] = acc[mi][ni][r] + bias[gcol] + resid[o];
      }
}

// ---------------- Fused relative attention --------------------------------
// One head per 512-thread block. k staged to LDS (multi-read operand);
// q/vT/rv8 direct from L2 (single-read). Windowed rel-terms (t2w/t3t),
// qk scratch in f16. LDS 45312B -> 3 blocks/CU.
__global__ __launch_bounds__(512, 6) void attn_kernel(
    const ushort_t* __restrict__ qb, const ushort_t* __restrict__ kb,
    const ushort_t* __restrict__ vtb,
    const ushort_t* __restrict__ rkp, const ushort_t* __restrict__ rqp,
    const unsigned char* __restrict__ rv8, const float* __restrict__ c0_g,
    ushort_t* __restrict__ attn_out)
{
  __shared__ __align__(16) char smem[45312];
  char* kS  = smem;             //  8192: k staged (pre-swizzled)
  char* qkB = smem + 8192;      //  8192: qk f16 [64]x128B swz
  char* t2w = smem + 16384;     // 14464: 64 x 226B
  char* t3t = smem + 30848;     // 14464: 113 x 128B swz
  char* attnSB = smem;          // overlay post-softmax (8K, over kS)
  char* S8B = smem + 16384;     // overlay post-softmax (16K, over t2w)

  const int tid = threadIdx.x, lane = tid & 63, wid = tid >> 6;
  const int ib = wid >> 1, half = wid & 1;
  const int l15 = lane & 15, lh = lane >> 4;
  const int rowA = ib*16 + l15;
  const int bh = blockIdx.x;
  const ushort_t* q = qb + ((size_t)bh << 12);

  // stage k (8KB, one 16B DMA per thread); q fragments direct
  gload_lds16((const char*)kb + ((size_t)bh << 13) + tid*16, kS + tid*16);
  short8 qf0 = GFRAG(q, rowA, lh);
  short8 qf1 = GFRAG(q, rowA, 4+lh);
  bar_full();  // kS + qf ready

  const int ibase = ib*16 + lh*4;
  int baseR[4], i226[4];
#pragma unroll
  for (int r = 0; r < 4; ++r) {
    const int i = ibase + r;
    baseR[r] = (i >> 3)*15 + (i & 7);
    i226[r] = i*226;
  }

  // ---- P1a: QK^T (wave pair splits jb), store f16 to qkB -----------------
#pragma unroll
  for (int t = 0; t < 2; ++t) {
    const int jb = half*2 + t;
    const int rowK = jb*16 + l15;
    short8 b0 = LDSF(kS, rowK, lh);
    short8 b1 = LDSF(kS, rowK, 4+lh);
    f32x4 a = {};
    a = __builtin_amdgcn_mfma_f32_16x16x32_bf16(qf0, b0, a, 0,0,0);
    a = __builtin_amdgcn_mfma_f32_16x16x32_bf16(qf1, b1, a, 0,0,0);
    const int gcol = jb*16 + l15;
#pragma unroll
    for (int r = 0; r < 4; ++r) {
      const int i = ibase + r;
      *(ushort_t*)(qkB + i*128 + (((gcol>>3) ^ (i&7))<<4) + (gcol&7)*2)
          = f2h(a[r]);
    }
  }

  // ---- P1b: t2 = q @ rel_k^T, windowed store (c0 folded) -----------------
#pragma unroll
  for (int sp = 0; sp < 4; ++sp) {
    int rowr[2]; short8 lb[4]; float c0v[2];
#pragma unroll
    for (int cc = 0; cc < 2; ++cc) {
      rowr[cc] = (half*8 + sp*2 + cc)*16 + l15;
      lb[cc*2]   = *(const short8*)(rkp + rowr[cc]*64 + lh*8);
      lb[cc*2+1] = *(const short8*)(rkp + rowr[cc]*64 + 32 + lh*8);
      c0v[cc] = c0_g[rowr[cc]];
    }
    f32x4 a2[2] = {};
#pragma unroll
    for (int cc = 0; cc < 2; ++cc) {
      a2[cc] = __builtin_amdgcn_mfma_f32_16x16x32_bf16(qf0, lb[cc*2],   a2[cc], 0,0,0);
      a2[cc] = __builtin_amdgcn_mfma_f32_16x16x32_bf16(qf1, lb[cc*2+1], a2[cc], 0,0,0);
    }
#pragma unroll
    for (int cc = 0; cc < 2; ++cc)
#pragma unroll
      for (int r = 0; r < 4; ++r) {
        const unsigned c = (unsigned)(rowr[cc] - baseR[r]);
        if (c <= 112u)
          *(ushort_t*)(t2w + i226[r] + c*2) = f2bf(a2[cc][r] + c0v[cc]);
      }
  }

  // ---- P1c: t3 = k @ rel_q^T (pre-scaled), transposed windowed store -----
  {
    short8 kf0 = LDSF(kS, rowA, lh);
    short8 kf1 = LDSF(kS, rowA, 4+lh);
#pragma unroll
    for (int sp = 0; sp < 4; ++sp) {
      int rowr[2]; short8 lb[4];
#pragma unroll
      for (int cc = 0; cc < 2; ++cc) {
        rowr[cc] = (half*8 + sp*2 + cc)*16 + l15;
        lb[cc*2]   = *(const short8*)(rqp + rowr[cc]*64 + lh*8);
        lb[cc*2+1] = *(const short8*)(rqp + rowr[cc]*64 + 32 + lh*8);
      }
      f32x4 a3[2] = {};
#pragma unroll
      for (int cc = 0; cc < 2; ++cc) {
        a3[cc] = __builtin_amdgcn_mfma_f32_16x16x32_bf16(kf0, lb[cc*2],   a3[cc], 0,0,0);
        a3[cc] = __builtin_amdgcn_mfma_f32_16x16x32_bf16(kf1, lb[cc*2+1], a3[cc], 0,0,0);
      }
#pragma unroll
      for (int cc = 0; cc < 2; ++cc)
#pragma unroll
        for (int r = 0; r < 4; ++r) {
          const int j = ibase + r;
          const unsigned w = (unsigned)(rowr[cc] - 112 + baseR[r]);
          if (w <= 112u)
            *(ushort_t*)(t3t + w*128 + ((j*2) ^ ((w&7)<<4))) = f2bf(a3[cc][r]);
        }
    }
  }
  bar_lds();  // BAR1: qk/t2w/t3t complete

  // ---- P2: softmax --------------------------------------------------------
  const int i = tid >> 3, qq = tid & 7;
  const int base_i = (i >> 3)*15 + (i & 7);
  float av[8];
  {
    const char* t2row = t2w + i*226;
    const int cb = (7-qq)*15 + 7;
    ushort8 t3v = *(const ushort8*)(t3t + base_i*128 + ((qq*16) ^ ((base_i&7)<<4)));
    ushort8 qkv8 = *(const ushort8*)(qkB + i*128 + ((qq ^ (i&7))<<4));
    float mx = -1e30f;
#pragma unroll
    for (int e = 0; e < 8; ++e) {
      float v = h2f((ushort_t)qkv8[e])
              + bfu(*(const ushort_t*)(t2row + (cb - e)*2))
              + bfu((ushort_t)t3v[e]);
      av[e] = v; mx = fmaxf(mx, v);
    }
    mx = fmaxf(mx, __shfl_xor(mx, 1));
    mx = fmaxf(mx, __shfl_xor(mx, 2));
    mx = fmaxf(mx, __shfl_xor(mx, 4));
    float s = 0;
#pragma unroll
    for (int e = 0; e < 8; ++e) { float ev = __expf(av[e]-mx); av[e] = ev; s += ev; }
    s += __shfl_xor(s, 1); s += __shfl_xor(s, 2); s += __shfl_xor(s, 4);
    const float inv = 1.0f / s;
#pragma unroll
    for (int e = 0; e < 8; ++e) av[e] *= inv;
  }
  bar_lds();  // BAR2: all reads done; overlay may be rewritten

  // ---- P3: write attnS (bf16) + S8 (fp8 scatter, rr = rrb - jj) ----------
  {
    ushort8 w;
#pragma unroll
    for (int e = 0; e < 8; ++e) w[e] = f2bf(av[e]);
    *(ushort8*)(attnSB + i*128 + ((qq ^ (i&7))<<4)) = w;
#pragma unroll
    for (int u8 = 0; u8 < 4; ++u8)
      *(i64*)(S8B + i*256 + (((qq*4 + u8) ^ (i&7))<<3)) = 0;
    const int rrb = base_i + (7-qq)*15 + 7;
#pragma unroll
    for (int jj = 0; jj < 8; jj += 2) {
      int pk = __builtin_amdgcn_cvt_pk_fp8_f32(av[jj], av[jj+1], 0, 0);
      const int rr0 = rrb - jj;
      const int rr1 = rr0 - 1;
      *(unsigned char*)(S8B + i*256 + (((rr0>>3) ^ (i&7))<<3) + (rr0&7))
          = (unsigned char)(pk & 0xff);
      *(unsigned char*)(S8B + i*256 + (((rr1>>3) ^ (i&7))<<3) + (rr1&7))
          = (unsigned char)((pk >> 8) & 0xff);
    }
  }
  bar_lds();  // BAR3: attnS/S8 complete

  // ---- P4: out = attn @ v (bf16) + S @ rel_v^T (fp8), 2 tiles per wave ---
#pragma unroll
  for (int t = 0; t < 2; ++t) {
    const int db = half*2 + t;
    const int rowV = db*16 + l15;
    const ushort_t* vrow = vtb + ((size_t)bh << 12) + rowV*64;
    short8 bv0 = *(const short8*)(vrow + lh*8);
    short8 bv1 = *(const short8*)(vrow + 32 + lh*8);
    i64 b8v[8];
#pragma unroll
    for (int ks = 0; ks < 8; ++ks)
      b8v[ks] = *(const i64*)(rv8 + (size_t)rowV*256 + ks*32 + lh*8);
    f32x4 a = {};
#pragma unroll
    for (int ks = 0; ks < 8; ++ks) {
      i64 a8 = *(const i64*)(S8B + rowA*256 + (((ks*4+lh) ^ (rowA&7))<<3));
      a = __builtin_amdgcn_mfma_f32_16x16x32_fp8_fp8(a8, b8v[ks], a, 0,0,0);
    }
    {
      short8 aa0 = *(const short8*)(attnSB + rowA*128 + ((lh ^ (rowA&7))<<4));
      short8 aa1 = *(const short8*)(attnSB + rowA*128 + (((4+lh) ^ (rowA&7))<<4));
      a = __builtin_amdgcn_mfma_f32_16x16x32_bf16(aa0, bv0, a, 0,0,0);
      a = __builtin_amdgcn_mfma_f32_16x16x32_bf16(aa1, bv1, a, 0,0,0);
    }
    const int b_idx = bh >> 3, hh = bh & 7;
#pragma unroll
    for (int r = 0; r < 4; ++r)
      attn_out[((size_t)(b_idx*64 + ib*16 + lh*4 + r))*512 + hh*64 + db*16 + l15]
          = f2bf(a[r]);
  }
}

// ---------------------------------------------------------------------------
extern "C" void kernel_launch(void* const* d_in, const int* in_sizes, int n_in,
                              void* d_out, int out_size, void* d_ws, size_t ws_size,
                              hipStream_t stream)
{
  (void)in_sizes; (void)n_in; (void)out_size; (void)ws_size;
  const float* x     = (const float*)d_in[0];
  const float* w_qkv = (const float*)d_in[1];
  const float* w_proj= (const float*)d_in[2];
  const float* b_proj= (const float*)d_in[3];
  const float* w1    = (const float*)d_in[4];
  const float* b1    = (const float*)d_in[5];
  const float* w2    = (const float*)d_in[6];
  const float* b2    = (const float*)d_in[7];
  const float* g1    = (const float*)d_in[8];
  const float* be1   = (const float*)d_in[9];
  const float* g2    = (const float*)d_in[10];
  const float* be2   = (const float*)d_in[11];
  const float* rel_q = (const float*)d_in[12];
  const float* rel_k = (const float*)d_in[13];
  const float* rel_v = (const float*)d_in[14];

  char* ws = (char*)d_ws;
  const size_t MB = 1ull << 20;
  ushort_t* h      = (ushort_t*)(ws);            // 32MiB (reused as h2)
  ushort_t* qb     = (ushort_t*)(ws + 32*MB);
  ushort_t* kb     = (ushort_t*)(ws + 64*MB);
  ushort_t* vtb    = (ushort_t*)(ws + 96*MB);
  ushort_t* attn_o = (ushort_t*)(ws + 128*MB);
  ushort_t* ff     = (ushort_t*)(ws + 32*MB);    // aliases qb..attn_o (dead)
  float*    x_mid  = (float*)(ws + 160*MB);      // 64MiB
  char* wreg = ws + 224*MB;
  ushort_t* wqkvT = (ushort_t*)(wreg);
  ushort_t* wprojT= (ushort_t*)(wreg + 1572864);
  ushort_t* w1T   = (ushort_t*)(wreg + 2097152);
  ushort_t* w2T   = (ushort_t*)(wreg + 4194304);
  ushort_t*      rkp  = (ushort_t*)(wreg + 6291456);   // 256x64 bf16
  ushort_t*      rqp  = (ushort_t*)(wreg + 6324224);   // 256x64 bf16
  unsigned char* rv8  = (unsigned char*)(wreg + 6356992); // 64x256 fp8
  float*         c0_s = (float*)(wreg + 6373376);       // f32[256]

  wt_kernel<<<dim3(8,24), 256, 0, stream>>>(w_qkv, wqkvT, 512, 1536);
  wt_kernel<<<dim3(8,8),  256, 0, stream>>>(w_proj, wprojT, 512, 512);
  wt_kernel<<<dim3(8,32), 256, 0, stream>>>(w1, w1T, 512, 2048);
  wt_kernel<<<dim3(32,8), 256, 0, stream>>>(w2, w2T, 2048, 512);
  prep_rel_kernel<<<64, 256, 0, stream>>>(rel_q, rel_k, rel_v,
      rqp, rkp, rv8, c0_s);

  ln_kernel<<<8192, 256, 0, stream>>>(x, g1, be1, h);
  gemm_kernel<0><<<dim3(128,6), 512, 0, stream>>>(h, wqkvT, 32768, 1536, 512,
      nullptr, nullptr, qb, kb, vtb);
  attn_kernel<<<4096, 512, 0, stream>>>(qb, kb, vtb,
      rkp, rqp, rv8, c0_s, attn_o);
  gemm128_br<<<dim3(256,4), 256, 0, stream>>>(attn_o, wprojT, 32768, 512, 512,
      b_proj, x, x_mid);
  ln_kernel<<<8192, 256, 0, stream>>>(x_mid, g2, be2, h);
  gemm_kernel<2><<<dim3(128,8), 512, 0, stream>>>(h, w1T, 32768, 2048, 512,
      b1, ff, nullptr, nullptr, nullptr);
  gemm128_br<<<dim3(256,4), 256, 0, stream>>>(ff, w2T, 32768, 512, 2048,
      b2, x_mid, (float*)d_out);
}

// Round 12
// 581.553 us; speedup vs baseline: 1.0499x; 1.0378x over previous
//
#include <hip/hip_runtime.h>
#include <hip/hip_bf16.h>

typedef unsigned short ushort_t;
typedef __attribute__((ext_vector_type(8))) short short8;
typedef __attribute__((ext_vector_type(8))) unsigned short ushort8;
typedef __attribute__((ext_vector_type(4))) float f32x4;
typedef long long i64;

__device__ __forceinline__ ushort_t f2bf(float f) {
  union { float f; unsigned int u; } c; c.f = f;
  unsigned int u = c.u;
  return (ushort_t)((u + 0x7fffu + ((u >> 16) & 1u)) >> 16);
}
__device__ __forceinline__ float bfu(ushort_t u) {
  union { unsigned int u; float f; } c; c.u = ((unsigned int)u) << 16; return c.f;
}
__device__ __forceinline__ ushort_t f2h(float f) {
  union { _Float16 h; ushort_t u; } c; c.h = (_Float16)f; return c.u;
}
__device__ __forceinline__ float h2f(ushort_t u) {
  union { ushort_t u; _Float16 h; } c; c.u = u; return (float)c.h;
}

__device__ __forceinline__ void gload_lds16(const void* g, void* l) {
  __builtin_amdgcn_global_load_lds(
      (__attribute__((address_space(1))) void*)(void*)g,
      (__attribute__((address_space(3))) void*)l, 16, 0, 0);
}

__device__ __forceinline__ void bar_lds() {
  asm volatile("s_waitcnt lgkmcnt(0)" ::: "memory");
  __builtin_amdgcn_s_barrier();
  asm volatile("" ::: "memory");
}
__device__ __forceinline__ void bar_full() {
  asm volatile("s_waitcnt vmcnt(0) lgkmcnt(0)" ::: "memory");
  __builtin_amdgcn_s_barrier();
  asm volatile("" ::: "memory");
}

// swizzled fragment reads (16B granule XOR within 128B row)
#define GFRAG(p, row, g) \
  (*(const short8*)((p) + (row)*64 + ((((g) ^ ((row)&7))) << 3)))      // elem base
#define LDSF(base, row, g) \
  (*(const short8*)((base) + (row)*128 + ((((g) ^ ((row)&7))) << 4)))  // byte base

// ---------------- LayerNorm: f32 in -> bf16 out, D=512, one row per wave ----
__global__ __launch_bounds__(256) void ln_kernel(
    const float* __restrict__ x, const float* __restrict__ g,
    const float* __restrict__ be, ushort_t* __restrict__ out)
{
  const int lane = threadIdx.x & 63, wid = threadIdx.x >> 6;
  const size_t row = (size_t)blockIdx.x * 4 + wid;
  const float* xr = x + row * 512 + lane * 8;
  float4 v0 = *(const float4*)xr;
  float4 v1 = *(const float4*)(xr + 4);
  float vv[8] = {v0.x,v0.y,v0.z,v0.w,v1.x,v1.y,v1.z,v1.w};
  float s = 0;
#pragma unroll
  for (int e = 0; e < 8; ++e) s += vv[e];
#pragma unroll
  for (int o = 1; o < 64; o <<= 1) s += __shfl_xor(s, o);
  float mu = s * (1.0f/512.0f);
  float sq = 0;
#pragma unroll
  for (int e = 0; e < 8; ++e) { float d = vv[e]-mu; sq += d*d; }
#pragma unroll
  for (int o = 1; o < 64; o <<= 1) sq += __shfl_xor(sq, o);
  float rinv = rsqrtf(sq * (1.0f/512.0f) + 1e-5f);
  const float* gp = g + lane*8; const float* bp = be + lane*8;
  float4 ga = *(const float4*)gp, gb = *(const float4*)(gp+4);
  float4 ba = *(const float4*)bp, bb4 = *(const float4*)(bp+4);
  float gg[8] = {ga.x,ga.y,ga.z,ga.w,gb.x,gb.y,gb.z,gb.w};
  float bb[8] = {ba.x,ba.y,ba.z,ba.w,bb4.x,bb4.y,bb4.z,bb4.w};
  ushort8 o8;
#pragma unroll
  for (int e = 0; e < 8; ++e) o8[e] = f2bf((vv[e]-mu)*rinv*gg[e] + bb[e]);
  *(ushort8*)(out + row*512 + lane*8) = o8;
}

// ---------------- Weight transpose (tiled, coalesced both sides) -----------
__global__ __launch_bounds__(256) void wt_kernel(
    const float* __restrict__ w, ushort_t* __restrict__ wT, int K, int N)
{
  __shared__ float t[64][65];
  const int k0 = blockIdx.x * 64, n0 = blockIdx.y * 64;
  const int c = threadIdx.x & 63, r4 = threadIdx.x >> 6;
#pragma unroll
  for (int rr = 0; rr < 64; rr += 4)
    t[rr + r4][c] = w[(size_t)(k0 + rr + r4) * N + n0 + c];
  __syncthreads();
#pragma unroll
  for (int rr = 0; rr < 64; rr += 4)
    wT[(size_t)(n0 + rr + r4) * K + k0 + c] = f2bf(t[c][rr + r4]);
}

// ---------------- Rel-table prep ------------------------------------------
__global__ __launch_bounds__(256) void prep_rel_kernel(
    const float* __restrict__ rq, const float* __restrict__ rk,
    const float* __restrict__ rv,
    ushort_t* __restrict__ rqp, ushort_t* __restrict__ rkp,
    unsigned char* __restrict__ rv8, float* __restrict__ c0_s)
{
  int id = blockIdx.x * 256 + threadIdx.x;
  if (id < 256*64) {
    int r = id >> 6;
    rqp[id] = (r < 225) ? f2bf(rq[id] * 0.125f) : (ushort_t)0;
    rkp[id] = (r < 225) ? f2bf(rk[id]) : (ushort_t)0;
  }
  if (id < 64*256) {
    int d = id >> 8, r = id & 255;
    float vv = (r < 225) ? rv[r*64+d] : 0.0f;
    int pk = __builtin_amdgcn_cvt_pk_fp8_f32(vv, vv, 0, 0);
    rv8[id] = (unsigned char)(pk & 0xff);
  }
  if (id < 256) {
    float s = 0;
    if (id < 225)
      for (int d2 = 0; d2 < 64; ++d2) s += rq[id*64+d2]*rk[id*64+d2];
    c0_s[id] = s * 0.125f;
  }
}

// ---------------- bf16 GEMM 256x256 tile, BK=64, 512 thr, 128KB LDS --------
// 1-D grid, XCD-chunked: wg=(bid&7)*(nwg/8)+(bid>>3); m=wg/NN, n=wg%NN so
// blocks sharing an A-panel run consecutively on the SAME XCD.
// EPI 0: scatter qkv (XOR-swizzled q/k head tiles, linear vT)
// EPI 2: relu(+bias) -> bf16
template<int EPI>
__global__ __launch_bounds__(512, 2) void gemm_kernel(
    const ushort_t* __restrict__ A, const ushort_t* __restrict__ Bt,
    int M, int N, int K, int NN,
    const float* __restrict__ bias,
    ushort_t* __restrict__ outb,
    ushort_t* __restrict__ qb, ushort_t* __restrict__ kb,
    ushort_t* __restrict__ vtb)
{
  __shared__ __align__(16) ushort_t lds[65536];  // 2 x (A 32KB + B 32KB)
  const int tid = threadIdx.x, lane = tid & 63, wid = tid >> 6;
  const int nwg = gridDim.x;
  const int wg = (blockIdx.x & 7) * (nwg >> 3) + (blockIdx.x >> 3);
  const int m_t = (unsigned)wg / (unsigned)NN;
  const int n_t = wg - m_t * NN;
  const int m0 = m_t * 256, n0 = n_t * 256;
  const int l15 = lane & 15, lh = lane >> 4;
  const int wm = wid >> 2, wn = wid & 3;

  f32x4 acc[8][4] = {};
  const int NT = K >> 6;

  auto stage = [&](int buf, int kt) {
    const int k0 = kt << 6;
#pragma unroll
    for (int p = 0; p < 4; ++p) {
      const int lofs = p*8192 + tid*16;
      const int row = lofs >> 7;
      const int sc = ((tid & 7) ^ (row & 7)) << 3;
      gload_lds16(A  + (size_t)(m0 + row) * K + (k0 + sc),
                  &lds[buf*32768 + (lofs >> 1)]);
      gload_lds16(Bt + (size_t)(n0 + row) * K + (k0 + sc),
                  &lds[buf*32768 + 16384 + (lofs >> 1)]);
    }
  };

  stage(0, 0);
  __syncthreads();
  for (int t = 0; t < NT; ++t) {
    if (t + 1 < NT) stage((t+1) & 1, t+1);
    const ushort_t* Ab = &lds[(t&1)*32768];
    const ushort_t* Bb = Ab + 16384;
    short8 bfr[4][2];
#pragma unroll
    for (int ni = 0; ni < 4; ++ni) {
      const int row = wn*64 + ni*16 + l15;
#pragma unroll
      for (int kh = 0; kh < 2; ++kh)
        bfr[ni][kh] = *(const short8*)((const char*)Bb + row*128 +
                                       (((kh*4+lh) ^ (row&7))<<4));
    }
#pragma unroll
    for (int mi = 0; mi < 8; ++mi) {
      const int row = wm*128 + mi*16 + l15;
      short8 a0 = *(const short8*)((const char*)Ab + row*128 + ((lh     ^ (row&7))<<4));
      short8 a1 = *(const short8*)((const char*)Ab + row*128 + (((4+lh) ^ (row&7))<<4));
#pragma unroll
      for (int ni = 0; ni < 4; ++ni) {
        acc[mi][ni] = __builtin_amdgcn_mfma_f32_16x16x32_bf16(a0, bfr[ni][0], acc[mi][ni], 0,0,0);
        acc[mi][ni] = __builtin_amdgcn_mfma_f32_16x16x32_bf16(a1, bfr[ni][1], acc[mi][ni], 0,0,0);
      }
    }
    __syncthreads();
  }

#pragma unroll
  for (int mi = 0; mi < 8; ++mi)
#pragma unroll
    for (int ni = 0; ni < 4; ++ni)
#pragma unroll
      for (int r = 0; r < 4; ++r) {
        const int grow = m0 + wm*128 + mi*16 + lh*4 + r;
        const int gcol = n0 + wn*64 + ni*16 + l15;
        const float v = acc[mi][ni][r];
        if constexpr (EPI == 0) {
          const int sel = gcol >> 9, c5 = gcol & 511;
          const int hh = c5 >> 6, d = c5 & 63;
          const size_t bh = (size_t)((grow >> 6) * 8 + hh);
          const int i = grow & 63;
          if (sel == 0)
            qb[(bh<<12) + i*64 + (((d>>3)^(i&7))<<3) + (d&7)] = f2bf(v * 0.125f);
          else if (sel == 1)
            kb[(bh<<12) + i*64 + (((d>>3)^(i&7))<<3) + (d&7)] = f2bf(v);
          else
            vtb[(bh<<12) + d*64 + i] = f2bf(v);
        } else {
          float t2 = v + bias[gcol];
          outb[(size_t)grow * N + gcol] = f2bf(t2 > 0.0f ? t2 : 0.0f);
        }
      }
}

// ---------------- bf16 GEMM 128x128 tile, 1-D grid XCD-chunked -------------
// outf = A@Bt^T + bias + resid (f32)
__global__ __launch_bounds__(256) void gemm128_br(
    const ushort_t* __restrict__ A, const ushort_t* __restrict__ Bt,
    int M, int N, int K, int NN,
    const float* __restrict__ bias, const float* __restrict__ resid,
    float* __restrict__ outf)
{
  __shared__ __align__(16) ushort_t lds[32768];
  const int tid = threadIdx.x, lane = tid & 63, wid = tid >> 6;
  const int nwg = gridDim.x;
  const int wg = (blockIdx.x & 7) * (nwg >> 3) + (blockIdx.x >> 3);
  const int m_t = (unsigned)wg / (unsigned)NN;
  const int n_t = wg - m_t * NN;
  const int m0 = m_t * 128, n0 = n_t * 128;
  const int l15 = lane & 15, lh = lane >> 4;
  const int wm = wid >> 1, wn = wid & 1;

  f32x4 acc[4][4] = {};
  const int NT = K >> 6;

  auto stage = [&](int buf, int kt) {
    const int k0 = kt << 6;
#pragma unroll
    for (int p = 0; p < 4; ++p) {
      const int lofs = p*4096 + wid*1024;
      const int row = (lofs + lane*16) >> 7;
      const int sc = ((lane & 7) ^ (row & 7)) << 3;
      gload_lds16(A  + (size_t)(m0 + row) * K + (k0 + sc),
                  &lds[buf*16384 + (lofs >> 1)]);
      gload_lds16(Bt + (size_t)(n0 + row) * K + (k0 + sc),
                  &lds[buf*16384 + 8192 + (lofs >> 1)]);
    }
  };

  stage(0, 0);
  __syncthreads();
  for (int t = 0; t < NT; ++t) {
    if (t + 1 < NT) stage((t+1) & 1, t+1);
    const ushort_t* Ab = &lds[(t&1)*16384];
    const ushort_t* Bb = Ab + 8192;
#pragma unroll
    for (int kh = 0; kh < 2; ++kh) {
      const int slotk = kh*4 + lh;
      short8 af[4], bf[4];
#pragma unroll
      for (int mi = 0; mi < 4; ++mi) {
        int row = wm*64 + mi*16 + l15;
        af[mi] = *(const short8*)((const char*)Ab + row*128 + ((slotk ^ (row&7))<<4));
      }
#pragma unroll
      for (int ni = 0; ni < 4; ++ni) {
        int row = wn*64 + ni*16 + l15;
        bf[ni] = *(const short8*)((const char*)Bb + row*128 + ((slotk ^ (row&7))<<4));
      }
#pragma unroll
      for (int mi = 0; mi < 4; ++mi)
#pragma unroll
        for (int ni = 0; ni < 4; ++ni)
          acc[mi][ni] = __builtin_amdgcn_mfma_f32_16x16x32_bf16(
              af[mi], bf[ni], acc[mi][ni], 0, 0, 0);
    }
    __syncthreads();
  }

#pragma unroll
  for (int mi = 0; mi < 4; ++mi)
#pragma unroll
    for (int ni = 0; ni < 4; ++ni)
#pragma unroll
      for (int r = 0; r < 4; ++r) {
        const int grow = m0 + wm*64 + mi*16 + lh*4 + r;
        const int gcol = n0 + wn*64 + ni*16 + l15;
        const size_t o = (size_t)grow * N + gcol;
        outf[o] = acc[mi][ni][r] + bias[gcol] + resid[o];
      }
}

// ---------------- Fused relative attention (unchanged from R11) ------------
__global__ __launch_bounds__(512, 6) void attn_kernel(
    const ushort_t* __restrict__ qb, const ushort_t* __restrict__ kb,
    const ushort_t* __restrict__ vtb,
    const ushort_t* __restrict__ rkp, const ushort_t* __restrict__ rqp,
    const unsigned char* __restrict__ rv8, const float* __restrict__ c0_g,
    ushort_t* __restrict__ attn_out)
{
  __shared__ __align__(16) char smem[45312];
  char* kS  = smem;             //  8192: k staged (pre-swizzled)
  char* qkB = smem + 8192;      //  8192: qk f16 [64]x128B swz
  char* t2w = smem + 16384;     // 14464: 64 x 226B
  char* t3t = smem + 30848;     // 14464: 113 x 128B swz
  char* attnSB = smem;          // overlay post-softmax (8K, over kS)
  char* S8B = smem + 16384;     // overlay post-softmax (16K, over t2w)

  const int tid = threadIdx.x, lane = tid & 63, wid = tid >> 6;
  const int ib = wid >> 1, half = wid & 1;
  const int l15 = lane & 15, lh = lane >> 4;
  const int rowA = ib*16 + l15;
  const int bh = blockIdx.x;
  const ushort_t* q = qb + ((size_t)bh << 12);

  gload_lds16((const char*)kb + ((size_t)bh << 13) + tid*16, kS + tid*16);
  short8 qf0 = GFRAG(q, rowA, lh);
  short8 qf1 = GFRAG(q, rowA, 4+lh);
  bar_full();

  const int ibase = ib*16 + lh*4;
  int baseR[4], i226[4];
#pragma unroll
  for (int r = 0; r < 4; ++r) {
    const int i = ibase + r;
    baseR[r] = (i >> 3)*15 + (i & 7);
    i226[r] = i*226;
  }

  // ---- P1a: QK^T ----------------------------------------------------------
#pragma unroll
  for (int t = 0; t < 2; ++t) {
    const int jb = half*2 + t;
    const int rowK = jb*16 + l15;
    short8 b0 = LDSF(kS, rowK, lh);
    short8 b1 = LDSF(kS, rowK, 4+lh);
    f32x4 a = {};
    a = __builtin_amdgcn_mfma_f32_16x16x32_bf16(qf0, b0, a, 0,0,0);
    a = __builtin_amdgcn_mfma_f32_16x16x32_bf16(qf1, b1, a, 0,0,0);
    const int gcol = jb*16 + l15;
#pragma unroll
    for (int r = 0; r < 4; ++r) {
      const int i = ibase + r;
      *(ushort_t*)(qkB + i*128 + (((gcol>>3) ^ (i&7))<<4) + (gcol&7)*2)
          = f2h(a[r]);
    }
  }

  // ---- P1b: t2 = q @ rel_k^T, windowed store (c0 folded) -----------------
#pragma unroll
  for (int sp = 0; sp < 4; ++sp) {
    int rowr[2]; short8 lb[4]; float c0v[2];
#pragma unroll
    for (int cc = 0; cc < 2; ++cc) {
      rowr[cc] = (half*8 + sp*2 + cc)*16 + l15;
      lb[cc*2]   = *(const short8*)(rkp + rowr[cc]*64 + lh*8);
      lb[cc*2+1] = *(const short8*)(rkp + rowr[cc]*64 + 32 + lh*8);
      c0v[cc] = c0_g[rowr[cc]];
    }
    f32x4 a2[2] = {};
#pragma unroll
    for (int cc = 0; cc < 2; ++cc) {
      a2[cc] = __builtin_amdgcn_mfma_f32_16x16x32_bf16(qf0, lb[cc*2],   a2[cc], 0,0,0);
      a2[cc] = __builtin_amdgcn_mfma_f32_16x16x32_bf16(qf1, lb[cc*2+1], a2[cc], 0,0,0);
    }
#pragma unroll
    for (int cc = 0; cc < 2; ++cc)
#pragma unroll
      for (int r = 0; r < 4; ++r) {
        const unsigned c = (unsigned)(rowr[cc] - baseR[r]);
        if (c <= 112u)
          *(ushort_t*)(t2w + i226[r] + c*2) = f2bf(a2[cc][r] + c0v[cc]);
      }
  }

  // ---- P1c: t3 = k @ rel_q^T (pre-scaled), transposed windowed store -----
  {
    short8 kf0 = LDSF(kS, rowA, lh);
    short8 kf1 = LDSF(kS, rowA, 4+lh);
#pragma unroll
    for (int sp = 0; sp < 4; ++sp) {
      int rowr[2]; short8 lb[4];
#pragma unroll
      for (int cc = 0; cc < 2; ++cc) {
        rowr[cc] = (half*8 + sp*2 + cc)*16 + l15;
        lb[cc*2]   = *(const short8*)(rqp + rowr[cc]*64 + lh*8);
        lb[cc*2+1] = *(const short8*)(rqp + rowr[cc]*64 + 32 + lh*8);
      }
      f32x4 a3[2] = {};
#pragma unroll
      for (int cc = 0; cc < 2; ++cc) {
        a3[cc] = __builtin_amdgcn_mfma_f32_16x16x32_bf16(kf0, lb[cc*2],   a3[cc], 0,0,0);
        a3[cc] = __builtin_amdgcn_mfma_f32_16x16x32_bf16(kf1, lb[cc*2+1], a3[cc], 0,0,0);
      }
#pragma unroll
      for (int cc = 0; cc < 2; ++cc)
#pragma unroll
        for (int r = 0; r < 4; ++r) {
          const int j = ibase + r;
          const unsigned w = (unsigned)(rowr[cc] - 112 + baseR[r]);
          if (w <= 112u)
            *(ushort_t*)(t3t + w*128 + ((j*2) ^ ((w&7)<<4))) = f2bf(a3[cc][r]);
        }
    }
  }
  bar_lds();  // BAR1

  // ---- P2: softmax --------------------------------------------------------
  const int i = tid >> 3, qq = tid & 7;
  const int base_i = (i >> 3)*15 + (i & 7);
  float av[8];
  {
    const char* t2row = t2w + i*226;
    const int cb = (7-qq)*15 + 7;
    ushort8 t3v = *(const ushort8*)(t3t + base_i*128 + ((qq*16) ^ ((base_i&7)<<4)));
    ushort8 qkv8 = *(const ushort8*)(qkB + i*128 + ((qq ^ (i&7))<<4));
    float mx = -1e30f;
#pragma unroll
    for (int e = 0; e < 8; ++e) {
      float v = h2f((ushort_t)qkv8[e])
              + bfu(*(const ushort_t*)(t2row + (cb - e)*2))
              + bfu((ushort_t)t3v[e]);
      av[e] = v; mx = fmaxf(mx, v);
    }
    mx = fmaxf(mx, __shfl_xor(mx, 1));
    mx = fmaxf(mx, __shfl_xor(mx, 2));
    mx = fmaxf(mx, __shfl_xor(mx, 4));
    float s = 0;
#pragma unroll
    for (int e = 0; e < 8; ++e) { float ev = __expf(av[e]-mx); av[e] = ev; s += ev; }
    s += __shfl_xor(s, 1); s += __shfl_xor(s, 2); s += __shfl_xor(s, 4);
    const float inv = 1.0f / s;
#pragma unroll
    for (int e = 0; e < 8; ++e) av[e] *= inv;
  }
  bar_lds();  // BAR2

  // ---- P3: write attnS (bf16) + S8 (fp8 scatter) --------------------------
  {
    ushort8 w;
#pragma unroll
    for (int e = 0; e < 8; ++e) w[e] = f2bf(av[e]);
    *(ushort8*)(attnSB + i*128 + ((qq ^ (i&7))<<4)) = w;
#pragma unroll
    for (int u8 = 0; u8 < 4; ++u8)
      *(i64*)(S8B + i*256 + (((qq*4 + u8) ^ (i&7))<<3)) = 0;
    const int rrb = base_i + (7-qq)*15 + 7;
#pragma unroll
    for (int jj = 0; jj < 8; jj += 2) {
      int pk = __builtin_amdgcn_cvt_pk_fp8_f32(av[jj], av[jj+1], 0, 0);
      const int rr0 = rrb - jj;
      const int rr1 = rr0 - 1;
      *(unsigned char*)(S8B + i*256 + (((rr0>>3) ^ (i&7))<<3) + (rr0&7))
          = (unsigned char)(pk & 0xff);
      *(unsigned char*)(S8B + i*256 + (((rr1>>3) ^ (i&7))<<3) + (rr1&7))
          = (unsigned char)((pk >> 8) & 0xff);
    }
  }
  bar_lds();  // BAR3

  // ---- P4: out = attn @ v (bf16) + S @ rel_v^T (fp8) ----------------------
#pragma unroll
  for (int t = 0; t < 2; ++t) {
    const int db = half*2 + t;
    const int rowV = db*16 + l15;
    const ushort_t* vrow = vtb + ((size_t)bh << 12) + rowV*64;
    short8 bv0 = *(const short8*)(vrow + lh*8);
    short8 bv1 = *(const short8*)(vrow + 32 + lh*8);
    i64 b8v[8];
#pragma unroll
    for (int ks = 0; ks < 8; ++ks)
      b8v[ks] = *(const i64*)(rv8 + (size_t)rowV*256 + ks*32 + lh*8);
    f32x4 a = {};
#pragma unroll
    for (int ks = 0; ks < 8; ++ks) {
      i64 a8 = *(const i64*)(S8B + rowA*256 + (((ks*4+lh) ^ (rowA&7))<<3));
      a = __builtin_amdgcn_mfma_f32_16x16x32_fp8_fp8(a8, b8v[ks], a, 0,0,0);
    }
    {
      short8 aa0 = *(const short8*)(attnSB + rowA*128 + ((lh ^ (rowA&7))<<4));
      short8 aa1 = *(const short8*)(attnSB + rowA*128 + (((4+lh) ^ (rowA&7))<<4));
      a = __builtin_amdgcn_mfma_f32_16x16x32_bf16(aa0, bv0, a, 0,0,0);
      a = __builtin_amdgcn_mfma_f32_16x16x32_bf16(aa1, bv1, a, 0,0,0);
    }
    const int b_idx = bh >> 3, hh = bh & 7;
#pragma unroll
    for (int r = 0; r < 4; ++r)
      attn_out[((size_t)(b_idx*64 + ib*16 + lh*4 + r))*512 + hh*64 + db*16 + l15]
          = f2bf(a[r]);
  }
}

// ---------------------------------------------------------------------------
extern "C" void kernel_launch(void* const* d_in, const int* in_sizes, int n_in,
                              void* d_out, int out_size, void* d_ws, size_t ws_size,
                              hipStream_t stream)
{
  (void)in_sizes; (void)n_in; (void)out_size; (void)ws_size;
  const float* x     = (const float*)d_in[0];
  const float* w_qkv = (const float*)d_in[1];
  const float* w_proj= (const float*)d_in[2];
  const float* b_proj= (const float*)d_in[3];
  const float* w1    = (const float*)d_in[4];
  const float* b1    = (const float*)d_in[5];
  const float* w2    = (const float*)d_in[6];
  const float* b2    = (const float*)d_in[7];
  const float* g1    = (const float*)d_in[8];
  const float* be1   = (const float*)d_in[9];
  const float* g2    = (const float*)d_in[10];
  const float* be2   = (const float*)d_in[11];
  const float* rel_q = (const float*)d_in[12];
  const float* rel_k = (const float*)d_in[13];
  const float* rel_v = (const float*)d_in[14];

  char* ws = (char*)d_ws;
  const size_t MB = 1ull << 20;
  ushort_t* h      = (ushort_t*)(ws);            // 32MiB (reused as h2)
  ushort_t* qb     = (ushort_t*)(ws + 32*MB);
  ushort_t* kb     = (ushort_t*)(ws + 64*MB);
  ushort_t* vtb    = (ushort_t*)(ws + 96*MB);
  ushort_t* attn_o = (ushort_t*)(ws + 128*MB);
  ushort_t* ff     = (ushort_t*)(ws + 32*MB);    // aliases qb..attn_o (dead)
  float*    x_mid  = (float*)(ws + 160*MB);      // 64MiB
  char* wreg = ws + 224*MB;
  ushort_t* wqkvT = (ushort_t*)(wreg);
  ushort_t* wprojT= (ushort_t*)(wreg + 1572864);
  ushort_t* w1T   = (ushort_t*)(wreg + 2097152);
  ushort_t* w2T   = (ushort_t*)(wreg + 4194304);
  ushort_t*      rkp  = (ushort_t*)(wreg + 6291456);   // 256x64 bf16
  ushort_t*      rqp  = (ushort_t*)(wreg + 6324224);   // 256x64 bf16
  unsigned char* rv8  = (unsigned char*)(wreg + 6356992); // 64x256 fp8
  float*         c0_s = (float*)(wreg + 6373376);       // f32[256]

  wt_kernel<<<dim3(8,24), 256, 0, stream>>>(w_qkv, wqkvT, 512, 1536);
  wt_kernel<<<dim3(8,8),  256, 0, stream>>>(w_proj, wprojT, 512, 512);
  wt_kernel<<<dim3(8,32), 256, 0, stream>>>(w1, w1T, 512, 2048);
  wt_kernel<<<dim3(32,8), 256, 0, stream>>>(w2, w2T, 2048, 512);
  prep_rel_kernel<<<64, 256, 0, stream>>>(rel_q, rel_k, rel_v,
      rqp, rkp, rv8, c0_s);

  ln_kernel<<<8192, 256, 0, stream>>>(x, g1, be1, h);
  gemm_kernel<0><<<768, 512, 0, stream>>>(h, wqkvT, 32768, 1536, 512, 6,
      nullptr, nullptr, qb, kb, vtb);
  attn_kernel<<<4096, 512, 0, stream>>>(qb, kb, vtb,
      rkp, rqp, rv8, c0_s, attn_o);
  gemm128_br<<<1024, 256, 0, stream>>>(attn_o, wprojT, 32768, 512, 512, 4,
      b_proj, x, x_mid);
  ln_kernel<<<8192, 256, 0, stream>>>(x_mid, g2, be2, h);
  gemm_kernel<2><<<1024, 512, 0, stream>>>(h, w1T, 32768, 2048, 512, 8,
      b1, ff, nullptr, nullptr, nullptr);
  gemm128_br<<<1024, 256, 0, stream>>>(ff, w2T, 32768, 512, 2048, 4,
      b2, x_mid, (float*)d_out);
}